// Round 19
// baseline (158.621 us; speedup 1.0000x reference)
//
#include <hip/hip_runtime.h>
#include <math.h>

#define EPSF 1e-6f

typedef __attribute__((ext_vector_type(8))) short short8;
typedef __attribute__((ext_vector_type(4))) float f32x4;
typedef __attribute__((ext_vector_type(4), aligned(8))) unsigned int uint4a;

constexpr int Bn = 2, Cn = 32, Dn = 64, Hn = 64, Wn = 64;
constexpr int HW  = Hn * Wn;          // 4096
constexpr int DHW = Dn * HW;          // 262144
constexpr int NVOX = Bn * DHW;        // 524288
constexpr size_t BS = (size_t)Cn * DHW;

// accum layout in ws:
// 0 hinge_num, 1 hinge_den, 2 warp_num, 3 warp_den,
// 4 l1_nz, 5 l1_yz, 6 l2_nz, 7 l2_yz, 8 nz_den, 9 yz_den,
// 10 cyc1, 11 cyc2, 12 smooth_sum

__device__ inline float sl1(float d) {
    float a = fabsf(d);
    return a < 1.f ? 0.5f * d * d : a - 0.5f;
}

__device__ inline int xcd_swz(int bid, int chunk) {
    return (bid & 7) * chunk + (bid >> 3);
}

__device__ inline float dpp_left(float v) {
    int r = __builtin_amdgcn_update_dpp(0, __float_as_int(v), 0x138, 0xF, 0xF, true);
    return __int_as_float(r);
}
__device__ inline float dpp_right(float v) {
    int r = __builtin_amdgcn_update_dpp(0, __float_as_int(v), 0x130, 0xF, 0xF, true);
    return __int_as_float(r);
}

__device__ inline unsigned int bf16b(float f) {
    return (__float_as_uint(f) + 0x8000u) >> 16;
}
__device__ inline unsigned int bfpack(float lo, float hi) {
    return bf16b(lo) | ((__float_as_uint(hi) + 0x8000u) & 0xffff0000u);
}
__device__ inline float bf2f(unsigned short u) {
    return __uint_as_float((unsigned int)u << 16);
}
__device__ inline float lo16(unsigned w) { return __uint_as_float(w << 16); }
__device__ inline float hi16(unsigned w) { return __uint_as_float(w & 0xffff0000u); }
// unpack channel j (0..3) from a uint2 holding 4 bf16 channels
__device__ inline float unpk(uint2 q, int j) {
    unsigned w = (j < 2) ? q.x : q.y;
    return (j & 1) ? hi16(w) : lo16(w);
}
__device__ inline float unpk4(uint4a q, int half, int j) {
    unsigned w = (j < 2) ? q[2 * half] : q[2 * half + 1];
    return (j & 1) ? hi16(w) : lo16(w);
}

// Trilinear gather helpers (f32 path)
struct PairGather {
    int   pidx[4];
    int   sel[4];
    float w0[4], w1[4];
};

__device__ inline void warp_pair_setup(float flx, float fly, float flz,
                                       int x, int y, int z,
                                       PairGather& pg, float& wsum) {
    float xs = (float)x + flx, ys = (float)y + fly, zs = (float)z + flz;
    float xf = floorf(xs), yf = floorf(ys), zf = floorf(zs);
    float fx = xs - xf, fy = ys - yf, fz = zs - zf;
    int xi = (int)xf, yi = (int)yf, zi = (int)zf;

    int x0c = min(max(xi, 0), Wn - 1);
    bool xv0 = (xi >= 0) && (xi < Wn);
    bool xv1 = (xi + 1 >= 0) && (xi + 1 < Wn);
    int sel = (xi >= 0 && xi < Wn - 1) ? 1 : 0;
    float wx0 = xv0 ? (1.f - fx) : 0.f;
    float wx1 = xv1 ? fx : 0.f;

    wsum = 0.f;
#pragma unroll
    for (int cz = 0; cz < 2; cz++) {
        int zz = zi + cz;
        bool zv = (zz >= 0) && (zz < Dn);
        int zc = min(max(zz, 0), Dn - 1);
        float wz = (cz ? fz : 1.f - fz) * (zv ? 1.f : 0.f);
#pragma unroll
        for (int cy = 0; cy < 2; cy++) {
            int yy = yi + cy;
            bool yv = (yy >= 0) && (yy < Hn);
            int yc = min(max(yy, 0), Hn - 1);
            float wy = (cy ? fy : 1.f - fy) * (yv ? 1.f : 0.f);
            int k = cz * 2 + cy;
            int sp = (zc * Hn + yc) * Wn + x0c;
            pg.pidx[k] = min(sp, DHW - 2);
            pg.sel[k] = sel;
            float wzy = wz * wy;
            pg.w0[k] = wzy * wx0;
            pg.w1[k] = wzy * wx1;
            wsum += pg.w0[k] + pg.w1[k];
        }
    }
}

__device__ inline float gather8(const float* __restrict__ slab, const PairGather& pg) {
    float g = 0.f;
#pragma unroll
    for (int k = 0; k < 4; k++) {
        float2 v = *reinterpret_cast<const float2*>(slab + pg.pidx[k]);
        float second = pg.sel[k] ? v.y : v.x;
        g = fmaf(v.x, pg.w0[k], g);
        g = fmaf(second, pg.w1[k], g);
    }
    return g;
}

// One-time: W1 (64x27 f32) -> padded bf16 [n][k] with stride 40, k<27 else 0.
__global__ void prep_kernel(const float* __restrict__ W1, ushort* __restrict__ W1bf) {
    int i = blockIdx.x * 256 + threadIdx.x;
    if (i < 64 * 32) {
        int n = i >> 5, k = i & 31;
        float val = (k < 27) ? W1[n * 27 + k] : 0.f;
        W1bf[n * 40 + k] = (ushort)bf16b(val);
    }
}

// Pack feat1 into channel-group planes: pk1[p][vox] = 4 bf16 channels (8B).
__global__ __launch_bounds__(256)
void pack_kernel(const float* __restrict__ f1, uint2* __restrict__ pk1) {
    int v = blockIdx.x * 256 + threadIdx.x;
    int b = v >> 18;
    int sp = v & (DHW - 1);
    const float* src = f1 + (size_t)b * BS + sp;
#pragma unroll
    for (int p = 0; p < 8; p++) {
        float c0 = src[(size_t)(4 * p + 0) * DHW];
        float c1 = src[(size_t)(4 * p + 1) * DHW];
        float c2 = src[(size_t)(4 * p + 2) * DHW];
        float c3 = src[(size_t)(4 * p + 3) * DHW];
        pk1[(size_t)p * NVOX + v] = make_uint2(bfpack(c0, c1), bfpack(c2, c3));
    }
}

// MFMA flow head (shared).
__device__ __forceinline__ void flow_head_mfma(
        float* acc, ushort (*ccS)[64][40], int wid, int lane,
        const ushort* __restrict__ W1bf, const float* __restrict__ b1,
        const float* __restrict__ W2, const float* __restrict__ b2,
        float* __restrict__ flow_out, size_t fb0,
        float& mfx, float& mfy, float& mfz) {
    float ss = 0.f;
#pragma unroll
    for (int i = 0; i < 27; i++) {
        float r = acc[i] > 0.f ? acc[i] : 0.f;
        acc[i] = r;
        ss = fmaf(r, r, ss);
    }
    float inv = 1.0f / (sqrtf(ss) + EPSF);
#pragma unroll
    for (int i = 0; i < 27; i++) acc[i] *= inv;

    {
        unsigned int pk[16];
#pragma unroll
        for (int i = 0; i < 13; i++) pk[i] = bfpack(acc[2 * i], acc[2 * i + 1]);
        pk[13] = bfpack(acc[26], 0.f);
        pk[14] = 0u; pk[15] = 0u;
        uint2* rowp = reinterpret_cast<uint2*>(&ccS[wid][lane][0]);
#pragma unroll
        for (int i = 0; i < 8; i++) rowp[i] = make_uint2(pk[2 * i], pk[2 * i + 1]);
    }

    int c0 = lane & 15, oct = lane >> 4;

    short8 bfr[4];
#pragma unroll
    for (int t = 0; t < 4; t++)
        bfr[t] = *reinterpret_cast<const short8*>(W1bf + (size_t)(t * 16 + c0) * 40 + oct * 8);

    f32x4 b1v[4], w2f0[4], w2f1[4], w2f2[4];
#pragma unroll
    for (int mt = 0; mt < 4; mt++) {
        b1v[mt]  = *reinterpret_cast<const f32x4*>(b1 + mt * 16 + oct * 4);
        w2f0[mt] = *reinterpret_cast<const f32x4*>(W2 + mt * 16 + oct * 4);
        w2f1[mt] = *reinterpret_cast<const f32x4*>(W2 + 64 + mt * 16 + oct * 4);
        w2f2[mt] = *reinterpret_cast<const f32x4*>(W2 + 128 + mt * 16 + oct * 4);
    }
    float bb0 = b2[0], bb1 = b2[1], bb2 = b2[2];

#pragma unroll
    for (int nt = 0; nt < 4; nt++) {
        short8 afr = *reinterpret_cast<const short8*>(&ccS[wid][nt * 16 + c0][oct * 8]);
        f32x4 ac[4];
#pragma unroll
        for (int mt = 0; mt < 4; mt++) {
            f32x4 zero = {0.f, 0.f, 0.f, 0.f};
            ac[mt] = __builtin_amdgcn_mfma_f32_16x16x32_bf16(bfr[mt], afr, zero, 0, 0, 0);
        }
        float p0 = 0.f, p1 = 0.f, p2 = 0.f;
#pragma unroll
        for (int mt = 0; mt < 4; mt++) {
#pragma unroll
            for (int rg = 0; rg < 4; rg++) {
                float h = ac[mt][rg] + b1v[mt][rg];
                h = fmaxf(h, 0.01f * h);
                p0 = fmaf(w2f0[mt][rg], h, p0);
                p1 = fmaf(w2f1[mt][rg], h, p1);
                p2 = fmaf(w2f2[mt][rg], h, p2);
            }
        }
        p0 += __shfl_xor(p0, 16); p0 += __shfl_xor(p0, 32);
        p1 += __shfl_xor(p1, 16); p1 += __shfl_xor(p1, 32);
        p2 += __shfl_xor(p2, 16); p2 += __shfl_xor(p2, 32);
        if (oct == nt) {
            int vox = nt * 16 + c0;              // == lane
            mfx = p0 + bb0; mfy = p1 + bb1; mfz = p2 + bb2;
            flow_out[fb0 + vox]           = mfx;
            flow_out[fb0 + DHW + vox]     = mfy;
            flow_out[fb0 + 2 * DHW + vox] = mfz;
        }
    }
}

__device__ __forceinline__ void fwd_losses_common(
        float mfx, float mfy, float mfz, float diff2,
        const float* __restrict__ flow_g, const float* __restrict__ mask_g,
        int lane, int y, int z, int b, size_t fb0, float* pv) {
    size_t fbase = fb0 + lane;
    float gx = flow_g[fbase], gy = flow_g[fbase + DHW], gz = flow_g[fbase + 2 * DHW];
    float mg = mask_g[(size_t)b * DHW + (size_t)z * HW + y * Wn + lane];

    float ag = fabsf(gx) + fabsf(gy) + fabsf(gz);
    float hmask = ag > 1.0f ? 1.f : 0.f;
    float hv = 0.2f - sqrtf(diff2 + EPSF);
    hv = hv > 0.f ? hv : 0.f;

    float dx0 = mfx - gx, dy0 = mfy - gy, dz0 = mfz - gz;
    float l1 = (sl1(dx0) + sl1(dy0) + sl1(dz0)) * (1.f / 3.f);
    float l2 = (dx0 * dx0 + dy0 * dy0 + dz0 * dz0) * (1.f / 3.f);
    float nz = (ag > 0.01f ? 1.f : 0.f) * mg;
    float yz = (1.f - nz) * mg;

    pv[0] = hv * hmask; pv[1] = hmask;
    pv[4] = l1 * nz;    pv[5] = l1 * yz;
    pv[6] = l2 * nz;    pv[7] = l2 * yz;
    pv[8] = nz;         pv[9] = yz;
}

// grouped craw store: planes [3g..3g+2] of acc -> one uint2 per group
__device__ __forceinline__ void craw_store(uint2* __restrict__ cg, size_t vidx,
                                           const float* acc) {
#pragma unroll
    for (int g = 0; g < 9; g++)
        cg[(size_t)g * NVOX + vidx] =
            make_uint2(bfpack(acc[3 * g], acc[3 * g + 1]), bfpack(acc[3 * g + 2], 0.f));
}

// ---------------- PACKED forward kernel ----------------
__global__ __launch_bounds__(256)
void corr_fwd_packed(const float* __restrict__ feat0, const uint2* __restrict__ pk1,
                     const ushort* __restrict__ W1bf, const float* __restrict__ b1,
                     const float* __restrict__ W2, const float* __restrict__ b2,
                     float* __restrict__ flow_forw,
                     const float* __restrict__ flow_g, const float* __restrict__ mask_g,
                     float* __restrict__ accum, uint2* __restrict__ cg) {
    __shared__ ushort ccS[4][64][40];

    int tid = threadIdx.x;
    int lane = tid & 63;
    int wid = __builtin_amdgcn_readfirstlane(tid >> 6);

    int R = xcd_swz(blockIdx.x, 256) * 4 + wid;
    int y = R & 63, z = (R >> 6) & 63, b = R >> 12;

    const uint2* rp[9];
    float rmask[9];
    {
        int idx = 0;
#pragma unroll
        for (int dz = -1; dz <= 1; dz++) {
#pragma unroll
            for (int dy = -1; dy <= 1; dy++, idx++) {
                int zz = z + dz, yy = y + dy;
                bool valid = (zz >= 0) && (zz < Dn) && (yy >= 0) && (yy < Hn);
                int zc = min(max(zz, 0), Dn - 1);
                int yc = min(max(yy, 0), Hn - 1);
                rp[idx] = pk1 + (size_t)b * DHW + (size_t)zc * HW + (size_t)yc * Wn;
                rmask[idx] = valid ? 1.f : 0.f;
            }
        }
    }
    const float* ap = feat0 + (size_t)b * BS + (size_t)z * HW + (size_t)y * Wn;

    float C[9], TL[9], TR[9];
#pragma unroll
    for (int r = 0; r < 9; r++) { C[r] = 0.f; TL[r] = 0.f; TR[r] = 0.f; }
    float diff2 = 0.f;

#pragma unroll 1
    for (int p = 0; p < 8; p++) {
        uint2 q[9];
#pragma unroll
        for (int r = 0; r < 9; r++) q[r] = rp[r][lane];
        float a4[4];
#pragma unroll
        for (int j = 0; j < 4; j++) a4[j] = ap[(size_t)j * DHW + lane];
        ap += (size_t)4 * DHW;
#pragma unroll
        for (int r = 0; r < 9; r++) rp[r] += NVOX;

#pragma unroll
        for (int j = 0; j < 4; j++) {
            float a = a4[j];
            float aL = dpp_left(a), aR = dpp_right(a);
            float ctr = unpk(q[4], j);
            float d = ctr - a;
            diff2 = fmaf(d, d, diff2);
#pragma unroll
            for (int r = 0; r < 9; r++) {
                float rv = unpk(q[r], j);
                C[r]  = fmaf(a,  rv, C[r]);
                TL[r] = fmaf(aL, rv, TL[r]);
                TR[r] = fmaf(aR, rv, TR[r]);
            }
        }
    }

    float acc[27];
#pragma unroll
    for (int r = 0; r < 9; r++) {
        acc[r * 3 + 0] = dpp_left(TR[r]) * rmask[r];
        acc[r * 3 + 1] = C[r] * rmask[r];
        acc[r * 3 + 2] = dpp_right(TL[r]) * rmask[r];
    }

    craw_store(cg, (size_t)R * 64 + lane, acc);

    size_t fb0 = (size_t)b * 3 * DHW + (size_t)z * HW + (size_t)y * Wn;
    float mfx, mfy, mfz;
    flow_head_mfma(acc, ccS, wid, lane, W1bf, b1, W2, b2, flow_forw, fb0,
                   mfx, mfy, mfz);

    float pv[10];
    fwd_losses_common(mfx, mfy, mfz, diff2, flow_g, mask_g, lane, y, z, b, fb0, pv);

    // feat-warp term: one uint4 (16B) per corner-plane covers both x-voxels
    {
        PairGather pgF; float wsum;
        warp_pair_setup(mfx, mfy, mfz, lane, y, z, pgF, wsum);
        const uint2* slab0 = pk1 + (size_t)b * DHW;
        const float* f0c = feat0 + (size_t)b * BS + (size_t)z * HW + (size_t)y * Wn + lane;
        float s = 0.f;
#pragma unroll 1
        for (int p = 0; p < 8; p++) {
            const uint2* slab = slab0 + (size_t)p * NVOX;
            float g4[4] = {0.f, 0.f, 0.f, 0.f};
#pragma unroll
            for (int k = 0; k < 4; k++) {
                uint4a q = *reinterpret_cast<const uint4a*>(slab + pgF.pidx[k]);
#pragma unroll
                for (int j = 0; j < 4; j++) {
                    float v0 = unpk4(q, 0, j);
                    float v1 = pgF.sel[k] ? unpk4(q, 1, j) : v0;
                    g4[j] = fmaf(v0, pgF.w0[k], g4[j]);
                    g4[j] = fmaf(v1, pgF.w1[k], g4[j]);
                }
            }
#pragma unroll
            for (int j = 0; j < 4; j++) {
                float d = g4[j] - f0c[(size_t)(4 * p + j) * DHW];
                s = fmaf(d, d, s);
            }
        }
        float vm = wsum * wsum;
        pv[2] = sqrtf(s + EPSF) * vm;
        pv[3] = vm;
    }

#pragma unroll
    for (int i = 0; i < 10; i++) {
        float val = pv[i];
        for (int off = 32; off; off >>= 1) val += __shfl_down(val, off, 64);
        pv[i] = val;
    }
    __shared__ float sred[10][4];
    if (lane == 0) {
#pragma unroll
        for (int i = 0; i < 10; i++) sred[i][wid] = pv[i];
    }
    __syncthreads();
    if (tid < 10) {
        atomicAdd(&accum[tid], sred[tid][0] + sred[tid][1] + sred[tid][2] + sred[tid][3]);
    }
}

// ---------------- f32 fallback forward kernel ----------------
__global__ __launch_bounds__(256)
void corr_fwd_f32(const float* __restrict__ feat0, const float* __restrict__ feat1,
                  const ushort* __restrict__ W1bf, const float* __restrict__ b1,
                  const float* __restrict__ W2, const float* __restrict__ b2,
                  float* __restrict__ flow_forw,
                  const float* __restrict__ flow_g, const float* __restrict__ mask_g,
                  float* __restrict__ accum, uint2* __restrict__ cg) {
    __shared__ ushort ccS[4][64][40];

    int tid = threadIdx.x;
    int lane = tid & 63;
    int wid = __builtin_amdgcn_readfirstlane(tid >> 6);

    int R = xcd_swz(blockIdx.x, 256) * 4 + wid;
    int y = R & 63, z = (R >> 6) & 63, b = R >> 12;

    const float* rp[9];
    float rmask[9];
    {
        int idx = 0;
#pragma unroll
        for (int dz = -1; dz <= 1; dz++) {
#pragma unroll
            for (int dy = -1; dy <= 1; dy++, idx++) {
                int zz = z + dz, yy = y + dy;
                bool valid = (zz >= 0) && (zz < Dn) && (yy >= 0) && (yy < Hn);
                int zc = min(max(zz, 0), Dn - 1);
                int yc = min(max(yy, 0), Hn - 1);
                rp[idx] = feat1 + (size_t)b * BS + (size_t)zc * HW + (size_t)yc * Wn;
                rmask[idx] = valid ? 1.f : 0.f;
            }
        }
    }
    const float* ap = feat0 + (size_t)b * BS + (size_t)z * HW + (size_t)y * Wn;

    float C[9], TL[9], TR[9];
#pragma unroll
    for (int r = 0; r < 9; r++) { C[r] = 0.f; TL[r] = 0.f; TR[r] = 0.f; }
    float diff2 = 0.f;

#pragma unroll 2
    for (int c = 0; c < Cn; c++) {
        float a = ap[lane];
        float rowv[9];
#pragma unroll
        for (int r = 0; r < 9; r++) rowv[r] = rp[r][lane];
        ap += DHW;
#pragma unroll
        for (int r = 0; r < 9; r++) rp[r] += DHW;

        float aL = dpp_left(a), aR = dpp_right(a);
        float d = rowv[4] - a;
        diff2 = fmaf(d, d, diff2);
#pragma unroll
        for (int r = 0; r < 9; r++) {
            float rv = rowv[r];
            C[r]  = fmaf(a,  rv, C[r]);
            TL[r] = fmaf(aL, rv, TL[r]);
            TR[r] = fmaf(aR, rv, TR[r]);
        }
    }

    float acc[27];
#pragma unroll
    for (int r = 0; r < 9; r++) {
        acc[r * 3 + 0] = dpp_left(TR[r]) * rmask[r];
        acc[r * 3 + 1] = C[r] * rmask[r];
        acc[r * 3 + 2] = dpp_right(TL[r]) * rmask[r];
    }

    craw_store(cg, (size_t)R * 64 + lane, acc);

    size_t fb0 = (size_t)b * 3 * DHW + (size_t)z * HW + (size_t)y * Wn;
    float mfx, mfy, mfz;
    flow_head_mfma(acc, ccS, wid, lane, W1bf, b1, W2, b2, flow_forw, fb0,
                   mfx, mfy, mfz);

    float pv[10];
    fwd_losses_common(mfx, mfy, mfz, diff2, flow_g, mask_g, lane, y, z, b, fb0, pv);

    {
        PairGather pgF; float wsum;
        warp_pair_setup(mfx, mfy, mfz, lane, y, z, pgF, wsum);
        const float* f1b = feat1 + (size_t)b * BS;
        const float* f0c = feat0 + (size_t)b * BS + (size_t)z * HW + (size_t)y * Wn + lane;
        float s = 0.f;
#pragma unroll 4
        for (int c = 0; c < Cn; c++) {
            float g = gather8(f1b + (size_t)c * DHW, pgF);
            float d = g - f0c[(size_t)c * DHW];
            s = fmaf(d, d, s);
        }
        float vm = wsum * wsum;
        pv[2] = sqrtf(s + EPSF) * vm;
        pv[3] = vm;
    }

#pragma unroll
    for (int i = 0; i < 10; i++) {
        float val = pv[i];
        for (int off = 32; off; off >>= 1) val += __shfl_down(val, off, 64);
        pv[i] = val;
    }
    __shared__ float sred[10][4];
    if (lane == 0) {
#pragma unroll
        for (int i = 0; i < 10; i++) sred[i][wid] = pv[i];
    }
    __syncthreads();
    if (tid < 10) {
        atomicAdd(&accum[tid], sred[tid][0] + sred[tid][1] + sred[tid][2] + sred[tid][3]);
    }
}

// Backward direction from grouped craw; cycle-2 fused (flow_forw is complete).
__global__ __launch_bounds__(256)
void corr_bwd_kernel(const uint2* __restrict__ cg,
                     const ushort* __restrict__ W1bf, const float* __restrict__ b1,
                     const float* __restrict__ W2, const float* __restrict__ b2,
                     float* __restrict__ flow_back, const float* __restrict__ flow_forw,
                     float* __restrict__ accum) {
    __shared__ ushort ccSb[4][64][40];

    int tid = threadIdx.x;
    int lane = tid & 63;
    int wid = __builtin_amdgcn_readfirstlane(tid >> 6);

    int R = xcd_swz(blockIdx.x, 256) * 4 + wid;
    int y = R & 63, z = (R >> 6) & 63, b = R >> 12;

    float acc[27];
#pragma unroll
    for (int sz = 0; sz < 3; sz++) {
#pragma unroll
        for (int sy = 0; sy < 3; sy++) {
            int cell = sz * 3 + sy;
            int zz = z + sz - 1, yy = y + sy - 1;
            bool valid = (zz >= 0) && (zz < Dn) && (yy >= 0) && (yy < Hn);
            int zc = min(max(zz, 0), Dn - 1);
            int yc = min(max(yy, 0), Hn - 1);
            float m = valid ? 1.f : 0.f;
            int gb = 8 - cell;                 // group holding planes {24,25,26}-base
            uint2 q = cg[(size_t)gb * NVOX + (size_t)b * DHW +
                         (size_t)zc * HW + (size_t)yc * Wn + lane];
            float s0 = lo16(q.x);              // plane 24-base
            float s1 = hi16(q.x);              // plane 25-base
            float s2 = lo16(q.y);              // plane 26-base
            int base = cell * 3;
            acc[base + 0] = dpp_left(s2) * m;
            acc[base + 1] = s1 * m;
            acc[base + 2] = dpp_right(s0) * m;
        }
    }

    size_t fb0 = (size_t)b * 3 * DHW + (size_t)z * HW + (size_t)y * Wn;
    float mfx, mfy, mfz;
    flow_head_mfma(acc, ccSb, wid, lane, W1bf, b1, W2, b2, flow_back, fb0,
                   mfx, mfy, mfz);

    // fused cycle 2: ff_al = backwarp(flow_forw, flow_back); flow_back at own
    // voxel is (mfx,mfy,mfz)
    PairGather pgB; float wsumB;
    warp_pair_setup(mfx, mfy, mfz, lane, y, z, pgB, wsumB);
    const float* ff_b = flow_forw + (size_t)b * 3 * DHW;
    float ffalx = gather8(ff_b, pgB);
    float ffaly = gather8(ff_b + DHW, pgB);
    float ffalz = gather8(ff_b + 2 * DHW, pgB);
    float cyc2 = sl1(mfx + ffalx) + sl1(mfy + ffaly) + sl1(mfz + ffalz);

    for (int off = 32; off; off >>= 1) cyc2 += __shfl_down(cyc2, off, 64);
    __shared__ float s2red[4];
    if (lane == 0) s2red[wid] = cyc2;
    __syncthreads();
    if (tid == 0)
        atomicAdd(&accum[11], s2red[0] + s2red[1] + s2red[2] + s2red[3]);
}

// Slim loss: cycle-1 + smoothness (cycle-2 moved into corr_bwd).
__global__ __launch_bounds__(256)
void slim_loss_kernel(const float* __restrict__ flowf, const float* __restrict__ flowb,
                      float* __restrict__ accum) {
    int tid = threadIdx.x;
    int v = xcd_swz(blockIdx.x, 256) * 256 + tid;
    int x = v & 63, y = (v >> 6) & 63, z = (v >> 12) & 63, b = v >> 18;

    size_t sp = (size_t)z * HW + y * Wn + x;
    size_t f3 = (size_t)b * 3 * DHW + sp;

    float ffx = flowf[f3], ffy = flowf[f3 + DHW], ffz = flowf[f3 + 2 * DHW];

    PairGather pgF; float wsumF;
    warp_pair_setup(ffx, ffy, ffz, x, y, z, pgF, wsumF);
    const float* fb_b = flowb + (size_t)b * 3 * DHW;
    float fbalx = gather8(fb_b, pgF);
    float fbaly = gather8(fb_b + DHW, pgF);
    float fbalz = gather8(fb_b + 2 * DHW, pgF);
    float cyc1 = sl1(ffx + fbalx) + sl1(ffy + fbaly) + sl1(ffz + fbalz);

    float sf = 0.f, sb2v = 0.f;
#pragma unroll
    for (int j = 0; j < 3; j++) {
        const float* pf = flowf + f3 + (size_t)j * DHW;
        float c0 = pf[0];
        float ddx = (x < Wn - 1) ? fabsf(pf[1] - c0) : 0.f;
        float ddy = (y < Hn - 1) ? fabsf(pf[Wn] - c0) : 0.f;
        sf += 2.f * ddx + ddy;
        const float* pb = flowb + f3 + (size_t)j * DHW;
        float c1 = pb[0];
        float ddx2 = (x < Wn - 1) ? fabsf(pb[1] - c1) : 0.f;
        float ddy2 = (y < Hn - 1) ? fabsf(pb[Wn] - c1) : 0.f;
        sb2v += 2.f * ddx2 + ddy2;
    }
    float smoothv = 0.5f * (sf * (1.f / 3.f) + sb2v * (1.f / 3.f));

    float pv[2] = { cyc1, smoothv };
#pragma unroll
    for (int i = 0; i < 2; i++) {
        float val = pv[i];
        for (int off = 32; off; off >>= 1) val += __shfl_down(val, off, 64);
        pv[i] = val;
    }
    __shared__ float sred[2][4];
    int lane = tid & 63, wid = tid >> 6;
    if (lane == 0) {
#pragma unroll
        for (int i = 0; i < 2; i++) sred[i][wid] = pv[i];
    }
    __syncthreads();
    if (tid < 2) {
        int dst = (tid == 0) ? 10 : 12;
        atomicAdd(&accum[dst], sred[tid][0] + sred[tid][1] + sred[tid][2] + sred[tid][3]);
    }
}

__global__ void finalize_kernel(const float* __restrict__ accum, float* __restrict__ out) {
    float hinge = accum[0] / (accum[1] + EPSF);
    float warp  = accum[2] / (accum[3] + EPSF);
    float l1b = 0.5f * (accum[4] / (accum[8] + EPSF) + accum[5] / (accum[9] + EPSF));
    float l2b = 0.5f * (accum[6] / (accum[8] + EPSF) + accum[7] / (accum[9] + EPSF));
    float n3 = 3.0f * (float)NVOX;
    float cyc = accum[10] / n3 + accum[11] / n3;
    float sm  = accum[12] / (float)NVOX;
    out[0] = hinge + cyc + l1b + l2b + warp + sm;
}

extern "C" void kernel_launch(void* const* d_in, const int* in_sizes, int n_in,
                              void* d_out, int out_size, void* d_ws, size_t ws_size,
                              hipStream_t stream) {
    const float* feat0  = (const float*)d_in[0];
    const float* feat1  = (const float*)d_in[1];
    const float* flow_g = (const float*)d_in[2];
    const float* mask_g = (const float*)d_in[3];
    const float* W1     = (const float*)d_in[4];
    const float* b1     = (const float*)d_in[5];
    const float* W2     = (const float*)d_in[6];
    const float* b2     = (const float*)d_in[7];

    float* out = (float*)d_out;
    float* accum = (float*)d_ws;                            // 13 floats @ 0
    ushort* W1bf = (ushort*)((char*)d_ws + 128);            // 5120 B
    const size_t FLOWB_OFF = 8192;
    const size_t FLOWB_BYTES = (size_t)Bn * 3 * DHW * sizeof(float);   // 6.29 MB
    float* flow_back = (float*)((char*)d_ws + FLOWB_OFF);
    const size_t CRAW_OFF = FLOWB_OFF + FLOWB_BYTES;
    const size_t CRAW_BYTES = (size_t)9 * NVOX * sizeof(uint2);        // 37.7 MB
    uint2* cg = (uint2*)((char*)d_ws + CRAW_OFF);
    const size_t PK1_OFF = CRAW_OFF + CRAW_BYTES;
    const size_t PK1_BYTES = (size_t)Cn * NVOX * sizeof(ushort);       // 33.6 MB
    uint2* pk1 = (uint2*)((char*)d_ws + PK1_OFF);
    float* flow_forw = out + 1;

    hipMemsetAsync(d_ws, 0, 64, stream);

    prep_kernel<<<dim3(8), dim3(256), 0, stream>>>(W1, W1bf);

    if (ws_size >= PK1_OFF + PK1_BYTES) {
        pack_kernel<<<dim3(NVOX / 256), dim3(256), 0, stream>>>(feat1, pk1);
        corr_fwd_packed<<<dim3(NVOX / 256), dim3(256), 0, stream>>>(
            feat0, pk1, W1bf, b1, W2, b2, flow_forw, flow_g, mask_g, accum, cg);
    } else {
        corr_fwd_f32<<<dim3(NVOX / 256), dim3(256), 0, stream>>>(
            feat0, feat1, W1bf, b1, W2, b2, flow_forw, flow_g, mask_g, accum, cg);
    }
    corr_bwd_kernel<<<dim3(NVOX / 256), dim3(256), 0, stream>>>(
        cg, W1bf, b1, W2, b2, flow_back, flow_forw, accum);
    slim_loss_kernel<<<dim3(NVOX / 256), dim3(256), 0, stream>>>(flow_forw, flow_back, accum);
    finalize_kernel<<<1, 1, 0, stream>>>(accum, out);
}

// Round 20
// 140.133 us; speedup vs baseline: 1.1319x; 1.1319x over previous
//
#include <hip/hip_runtime.h>
#include <math.h>

#define EPSF 1e-6f

typedef __attribute__((ext_vector_type(8))) short short8;
typedef __attribute__((ext_vector_type(4))) float f32x4;

constexpr int Bn = 2, Cn = 32, Dn = 64, Hn = 64, Wn = 64;
constexpr int HW  = Hn * Wn;          // 4096
constexpr int DHW = Dn * HW;          // 262144
constexpr int NVOX = Bn * DHW;        // 524288
constexpr size_t BS = (size_t)Cn * DHW;

// accum layout in ws:
// 0 hinge_num, 1 hinge_den, 2 warp_num, 3 warp_den,
// 4 l1_nz, 5 l1_yz, 6 l2_nz, 7 l2_yz, 8 nz_den, 9 yz_den,
// 10 cyc1, 11 cyc2, 12 smooth_sum

__device__ inline float sl1(float d) {
    float a = fabsf(d);
    return a < 1.f ? 0.5f * d * d : a - 0.5f;
}

__device__ inline int xcd_swz(int bid, int chunk) {
    return (bid & 7) * chunk + (bid >> 3);
}

__device__ inline float dpp_left(float v) {
    int r = __builtin_amdgcn_update_dpp(0, __float_as_int(v), 0x138, 0xF, 0xF, true);
    return __int_as_float(r);
}
__device__ inline float dpp_right(float v) {
    int r = __builtin_amdgcn_update_dpp(0, __float_as_int(v), 0x130, 0xF, 0xF, true);
    return __int_as_float(r);
}

__device__ inline unsigned int bf16b(float f) {
    return (__float_as_uint(f) + 0x8000u) >> 16;
}
__device__ inline unsigned int bfpack(float lo, float hi) {
    return bf16b(lo) | ((__float_as_uint(hi) + 0x8000u) & 0xffff0000u);
}
__device__ inline float bf2f(unsigned short u) {
    return __uint_as_float((unsigned int)u << 16);
}
// unpack channel j (0..3) from a uint2 holding 4 bf16 channels
__device__ inline float unpk(uint2 q, int j) {
    unsigned w = (j < 2) ? q.x : q.y;
    return (j & 1) ? __uint_as_float(w & 0xffff0000u)
                   : __uint_as_float(w << 16);
}

// Trilinear gather helpers (f32 path)
struct PairGather {
    int   pidx[4];
    int   sel[4];
    float w0[4], w1[4];
};

__device__ inline void warp_pair_setup(float flx, float fly, float flz,
                                       int x, int y, int z,
                                       PairGather& pg, float& wsum) {
    float xs = (float)x + flx, ys = (float)y + fly, zs = (float)z + flz;
    float xf = floorf(xs), yf = floorf(ys), zf = floorf(zs);
    float fx = xs - xf, fy = ys - yf, fz = zs - zf;
    int xi = (int)xf, yi = (int)yf, zi = (int)zf;

    int x0c = min(max(xi, 0), Wn - 1);
    bool xv0 = (xi >= 0) && (xi < Wn);
    bool xv1 = (xi + 1 >= 0) && (xi + 1 < Wn);
    int sel = (xi >= 0 && xi < Wn - 1) ? 1 : 0;
    float wx0 = xv0 ? (1.f - fx) : 0.f;
    float wx1 = xv1 ? fx : 0.f;

    wsum = 0.f;
#pragma unroll
    for (int cz = 0; cz < 2; cz++) {
        int zz = zi + cz;
        bool zv = (zz >= 0) && (zz < Dn);
        int zc = min(max(zz, 0), Dn - 1);
        float wz = (cz ? fz : 1.f - fz) * (zv ? 1.f : 0.f);
#pragma unroll
        for (int cy = 0; cy < 2; cy++) {
            int yy = yi + cy;
            bool yv = (yy >= 0) && (yy < Hn);
            int yc = min(max(yy, 0), Hn - 1);
            float wy = (cy ? fy : 1.f - fy) * (yv ? 1.f : 0.f);
            int k = cz * 2 + cy;
            int sp = (zc * Hn + yc) * Wn + x0c;
            pg.pidx[k] = min(sp, DHW - 2);
            pg.sel[k] = sel;
            float wzy = wz * wy;
            pg.w0[k] = wzy * wx0;
            pg.w1[k] = wzy * wx1;
            wsum += pg.w0[k] + pg.w1[k];
        }
    }
}

__device__ inline float gather8(const float* __restrict__ slab, const PairGather& pg) {
    float g = 0.f;
#pragma unroll
    for (int k = 0; k < 4; k++) {
        float2 v = *reinterpret_cast<const float2*>(slab + pg.pidx[k]);
        float second = pg.sel[k] ? v.y : v.x;
        g = fmaf(v.x, pg.w0[k], g);
        g = fmaf(second, pg.w1[k], g);
    }
    return g;
}

// One-time: W1 (64x27 f32) -> padded bf16 [n][k] with stride 40, k<27 else 0.
__global__ void prep_kernel(const float* __restrict__ W1, ushort* __restrict__ W1bf) {
    int i = blockIdx.x * 256 + threadIdx.x;
    if (i < 64 * 32) {
        int n = i >> 5, k = i & 31;
        float val = (k < 27) ? W1[n * 27 + k] : 0.f;
        W1bf[n * 40 + k] = (ushort)bf16b(val);
    }
}

// Pack feat1 into channel-group planes: pk1[p][vox] = 4 bf16 channels (8B).
__global__ __launch_bounds__(256)
void pack_kernel(const float* __restrict__ f1, uint2* __restrict__ pk1) {
    int v = blockIdx.x * 256 + threadIdx.x;    // voxel 0..NVOX-1
    int b = v >> 18;
    int sp = v & (DHW - 1);
    const float* src = f1 + (size_t)b * BS + sp;
#pragma unroll
    for (int p = 0; p < 8; p++) {
        float c0 = src[(size_t)(4 * p + 0) * DHW];
        float c1 = src[(size_t)(4 * p + 1) * DHW];
        float c2 = src[(size_t)(4 * p + 2) * DHW];
        float c3 = src[(size_t)(4 * p + 3) * DHW];
        pk1[(size_t)p * NVOX + v] = make_uint2(bfpack(c0, c1), bfpack(c2, c3));
    }
}

// MFMA flow head (shared): relu -> l2norm -> bf16 LDS -> W1 MFMA -> leaky ->
// W2 -> store; returns lane's own-voxel flow.
__device__ __forceinline__ void flow_head_mfma(
        float* acc, ushort (*ccS)[64][40], int wid, int lane,
        const ushort* __restrict__ W1bf, const float* __restrict__ b1,
        const float* __restrict__ W2, const float* __restrict__ b2,
        float* __restrict__ flow_out, size_t fb0,
        float& mfx, float& mfy, float& mfz) {
    float ss = 0.f;
#pragma unroll
    for (int i = 0; i < 27; i++) {
        float r = acc[i] > 0.f ? acc[i] : 0.f;
        acc[i] = r;
        ss = fmaf(r, r, ss);
    }
    float inv = 1.0f / (sqrtf(ss) + EPSF);
#pragma unroll
    for (int i = 0; i < 27; i++) acc[i] *= inv;

    {
        unsigned int pk[16];
#pragma unroll
        for (int i = 0; i < 13; i++) pk[i] = bfpack(acc[2 * i], acc[2 * i + 1]);
        pk[13] = bfpack(acc[26], 0.f);
        pk[14] = 0u; pk[15] = 0u;
        uint2* rowp = reinterpret_cast<uint2*>(&ccS[wid][lane][0]);
#pragma unroll
        for (int i = 0; i < 8; i++) rowp[i] = make_uint2(pk[2 * i], pk[2 * i + 1]);
    }

    int c0 = lane & 15, oct = lane >> 4;

    short8 bfr[4];
#pragma unroll
    for (int t = 0; t < 4; t++)
        bfr[t] = *reinterpret_cast<const short8*>(W1bf + (size_t)(t * 16 + c0) * 40 + oct * 8);

    f32x4 b1v[4], w2f0[4], w2f1[4], w2f2[4];
#pragma unroll
    for (int mt = 0; mt < 4; mt++) {
        b1v[mt]  = *reinterpret_cast<const f32x4*>(b1 + mt * 16 + oct * 4);
        w2f0[mt] = *reinterpret_cast<const f32x4*>(W2 + mt * 16 + oct * 4);
        w2f1[mt] = *reinterpret_cast<const f32x4*>(W2 + 64 + mt * 16 + oct * 4);
        w2f2[mt] = *reinterpret_cast<const f32x4*>(W2 + 128 + mt * 16 + oct * 4);
    }
    float bb0 = b2[0], bb1 = b2[1], bb2 = b2[2];

#pragma unroll
    for (int nt = 0; nt < 4; nt++) {
        short8 afr = *reinterpret_cast<const short8*>(&ccS[wid][nt * 16 + c0][oct * 8]);
        f32x4 ac[4];
#pragma unroll
        for (int mt = 0; mt < 4; mt++) {
            f32x4 zero = {0.f, 0.f, 0.f, 0.f};
            ac[mt] = __builtin_amdgcn_mfma_f32_16x16x32_bf16(bfr[mt], afr, zero, 0, 0, 0);
        }
        float p0 = 0.f, p1 = 0.f, p2 = 0.f;
#pragma unroll
        for (int mt = 0; mt < 4; mt++) {
#pragma unroll
            for (int rg = 0; rg < 4; rg++) {
                float h = ac[mt][rg] + b1v[mt][rg];
                h = fmaxf(h, 0.01f * h);
                p0 = fmaf(w2f0[mt][rg], h, p0);
                p1 = fmaf(w2f1[mt][rg], h, p1);
                p2 = fmaf(w2f2[mt][rg], h, p2);
            }
        }
        p0 += __shfl_xor(p0, 16); p0 += __shfl_xor(p0, 32);
        p1 += __shfl_xor(p1, 16); p1 += __shfl_xor(p1, 32);
        p2 += __shfl_xor(p2, 16); p2 += __shfl_xor(p2, 32);
        if (oct == nt) {
            int vox = nt * 16 + c0;              // == lane
            mfx = p0 + bb0; mfy = p1 + bb1; mfz = p2 + bb2;
            flow_out[fb0 + vox]           = mfx;
            flow_out[fb0 + DHW + vox]     = mfy;
            flow_out[fb0 + 2 * DHW + vox] = mfz;
        }
    }
}

// Fused epilogue losses (shared by packed/f32 forward kernels).
__device__ __forceinline__ void fwd_losses_common(
        float mfx, float mfy, float mfz, float diff2,
        const float* __restrict__ flow_g, const float* __restrict__ mask_g,
        int lane, int y, int z, int b, size_t fb0, float* pv) {
    size_t fbase = fb0 + lane;
    float gx = flow_g[fbase], gy = flow_g[fbase + DHW], gz = flow_g[fbase + 2 * DHW];
    float mg = mask_g[(size_t)b * DHW + (size_t)z * HW + y * Wn + lane];

    float ag = fabsf(gx) + fabsf(gy) + fabsf(gz);
    float hmask = ag > 1.0f ? 1.f : 0.f;
    float hv = 0.2f - sqrtf(diff2 + EPSF);
    hv = hv > 0.f ? hv : 0.f;

    float dx0 = mfx - gx, dy0 = mfy - gy, dz0 = mfz - gz;
    float l1 = (sl1(dx0) + sl1(dy0) + sl1(dz0)) * (1.f / 3.f);
    float l2 = (dx0 * dx0 + dy0 * dy0 + dz0 * dz0) * (1.f / 3.f);
    float nz = (ag > 0.01f ? 1.f : 0.f) * mg;
    float yz = (1.f - nz) * mg;

    pv[0] = hv * hmask; pv[1] = hmask;
    pv[4] = l1 * nz;    pv[5] = l1 * yz;
    pv[6] = l2 * nz;    pv[7] = l2 * yz;
    pv[8] = nz;         pv[9] = yz;
}

// ---------------- PACKED forward kernel ----------------
__global__ __launch_bounds__(256)
void corr_fwd_packed(const float* __restrict__ feat0, const uint2* __restrict__ pk1,
                     const ushort* __restrict__ W1bf, const float* __restrict__ b1,
                     const float* __restrict__ W2, const float* __restrict__ b2,
                     float* __restrict__ flow_forw,
                     const float* __restrict__ flow_g, const float* __restrict__ mask_g,
                     float* __restrict__ accum, ushort* __restrict__ craw) {
    __shared__ ushort ccS[4][64][40];

    int tid = threadIdx.x;
    int lane = tid & 63;
    int wid = __builtin_amdgcn_readfirstlane(tid >> 6);

    int R = xcd_swz(blockIdx.x, 256) * 4 + wid;
    int y = R & 63, z = (R >> 6) & 63, b = R >> 12;

    // 9 packed row pointers (plane 0), advanced by NVOX per channel-group
    const uint2* rp[9];
    float rmask[9];
    {
        int idx = 0;
#pragma unroll
        for (int dz = -1; dz <= 1; dz++) {
#pragma unroll
            for (int dy = -1; dy <= 1; dy++, idx++) {
                int zz = z + dz, yy = y + dy;
                bool valid = (zz >= 0) && (zz < Dn) && (yy >= 0) && (yy < Hn);
                int zc = min(max(zz, 0), Dn - 1);
                int yc = min(max(yy, 0), Hn - 1);
                rp[idx] = pk1 + (size_t)b * DHW + (size_t)zc * HW + (size_t)yc * Wn;
                rmask[idx] = valid ? 1.f : 0.f;
            }
        }
    }
    const float* ap = feat0 + (size_t)b * BS + (size_t)z * HW + (size_t)y * Wn;

    float C[9], TL[9], TR[9];
#pragma unroll
    for (int r = 0; r < 9; r++) { C[r] = 0.f; TL[r] = 0.f; TR[r] = 0.f; }
    float diff2 = 0.f;

#pragma unroll 1
    for (int p = 0; p < 8; p++) {
        uint2 q[9];
#pragma unroll
        for (int r = 0; r < 9; r++) q[r] = rp[r][lane];
        float a4[4];
#pragma unroll
        for (int j = 0; j < 4; j++) a4[j] = ap[(size_t)j * DHW + lane];
        ap += (size_t)4 * DHW;
#pragma unroll
        for (int r = 0; r < 9; r++) rp[r] += NVOX;

#pragma unroll
        for (int j = 0; j < 4; j++) {
            float a = a4[j];
            float aL = dpp_left(a), aR = dpp_right(a);
            float ctr = unpk(q[4], j);
            float d = ctr - a;
            diff2 = fmaf(d, d, diff2);
#pragma unroll
            for (int r = 0; r < 9; r++) {
                float rv = unpk(q[r], j);
                C[r]  = fmaf(a,  rv, C[r]);
                TL[r] = fmaf(aL, rv, TL[r]);
                TR[r] = fmaf(aR, rv, TR[r]);
            }
        }
    }

    float acc[27];
#pragma unroll
    for (int r = 0; r < 9; r++) {
        acc[r * 3 + 0] = dpp_left(TR[r]) * rmask[r];
        acc[r * 3 + 1] = C[r] * rmask[r];
        acc[r * 3 + 2] = dpp_right(TL[r]) * rmask[r];
    }

    size_t vidx = (size_t)R * 64 + lane;
#pragma unroll
    for (int i = 0; i < 27; i++)
        craw[(size_t)i * NVOX + vidx] = (ushort)bf16b(acc[i]);

    size_t fb0 = (size_t)b * 3 * DHW + (size_t)z * HW + (size_t)y * Wn;
    float mfx, mfy, mfz;
    flow_head_mfma(acc, ccS, wid, lane, W1bf, b1, W2, b2, flow_forw, fb0,
                   mfx, mfy, mfz);

    float pv[10];
    fwd_losses_common(mfx, mfy, mfz, diff2, flow_g, mask_g, lane, y, z, b, fb0, pv);

    // feat-warp term on PACKED feat1: per plane, 4 corners x 2 voxel loads
    {
        PairGather pgF; float wsum;
        warp_pair_setup(mfx, mfy, mfz, lane, y, z, pgF, wsum);
        const uint2* slab0 = pk1 + (size_t)b * DHW;
        const float* f0c = feat0 + (size_t)b * BS + (size_t)z * HW + (size_t)y * Wn + lane;
        float s = 0.f;
#pragma unroll 1
        for (int p = 0; p < 8; p++) {
            const uint2* slab = slab0 + (size_t)p * NVOX;
            float g4[4] = {0.f, 0.f, 0.f, 0.f};
#pragma unroll
            for (int k = 0; k < 4; k++) {
                uint2 q0 = slab[pgF.pidx[k]];
                uint2 q1 = slab[pgF.pidx[k] + 1];
#pragma unroll
                for (int j = 0; j < 4; j++) {
                    float v0 = unpk(q0, j);
                    float v1 = pgF.sel[k] ? unpk(q1, j) : v0;
                    g4[j] = fmaf(v0, pgF.w0[k], g4[j]);
                    g4[j] = fmaf(v1, pgF.w1[k], g4[j]);
                }
            }
#pragma unroll
            for (int j = 0; j < 4; j++) {
                float d = g4[j] - f0c[(size_t)(4 * p + j) * DHW];
                s = fmaf(d, d, s);
            }
        }
        float vm = wsum * wsum;
        pv[2] = sqrtf(s + EPSF) * vm;
        pv[3] = vm;
    }

#pragma unroll
    for (int i = 0; i < 10; i++) {
        float val = pv[i];
        for (int off = 32; off; off >>= 1) val += __shfl_down(val, off, 64);
        pv[i] = val;
    }
    __shared__ float sred[10][4];
    if (lane == 0) {
#pragma unroll
        for (int i = 0; i < 10; i++) sred[i][wid] = pv[i];
    }
    __syncthreads();
    if (tid < 10) {
        atomicAdd(&accum[tid], sred[tid][0] + sred[tid][1] + sred[tid][2] + sred[tid][3]);
    }
}

// ---------------- f32 fallback forward kernel ----------------
__global__ __launch_bounds__(256)
void corr_fwd_f32(const float* __restrict__ feat0, const float* __restrict__ feat1,
                  const ushort* __restrict__ W1bf, const float* __restrict__ b1,
                  const float* __restrict__ W2, const float* __restrict__ b2,
                  float* __restrict__ flow_forw,
                  const float* __restrict__ flow_g, const float* __restrict__ mask_g,
                  float* __restrict__ accum, ushort* __restrict__ craw) {
    __shared__ ushort ccS[4][64][40];

    int tid = threadIdx.x;
    int lane = tid & 63;
    int wid = __builtin_amdgcn_readfirstlane(tid >> 6);

    int R = xcd_swz(blockIdx.x, 256) * 4 + wid;
    int y = R & 63, z = (R >> 6) & 63, b = R >> 12;

    const float* rp[9];
    float rmask[9];
    {
        int idx = 0;
#pragma unroll
        for (int dz = -1; dz <= 1; dz++) {
#pragma unroll
            for (int dy = -1; dy <= 1; dy++, idx++) {
                int zz = z + dz, yy = y + dy;
                bool valid = (zz >= 0) && (zz < Dn) && (yy >= 0) && (yy < Hn);
                int zc = min(max(zz, 0), Dn - 1);
                int yc = min(max(yy, 0), Hn - 1);
                rp[idx] = feat1 + (size_t)b * BS + (size_t)zc * HW + (size_t)yc * Wn;
                rmask[idx] = valid ? 1.f : 0.f;
            }
        }
    }
    const float* ap = feat0 + (size_t)b * BS + (size_t)z * HW + (size_t)y * Wn;

    float C[9], TL[9], TR[9];
#pragma unroll
    for (int r = 0; r < 9; r++) { C[r] = 0.f; TL[r] = 0.f; TR[r] = 0.f; }
    float diff2 = 0.f;

#pragma unroll 2
    for (int c = 0; c < Cn; c++) {
        float a = ap[lane];
        float rowv[9];
#pragma unroll
        for (int r = 0; r < 9; r++) rowv[r] = rp[r][lane];
        ap += DHW;
#pragma unroll
        for (int r = 0; r < 9; r++) rp[r] += DHW;

        float aL = dpp_left(a), aR = dpp_right(a);
        float d = rowv[4] - a;
        diff2 = fmaf(d, d, diff2);
#pragma unroll
        for (int r = 0; r < 9; r++) {
            float rv = rowv[r];
            C[r]  = fmaf(a,  rv, C[r]);
            TL[r] = fmaf(aL, rv, TL[r]);
            TR[r] = fmaf(aR, rv, TR[r]);
        }
    }

    float acc[27];
#pragma unroll
    for (int r = 0; r < 9; r++) {
        acc[r * 3 + 0] = dpp_left(TR[r]) * rmask[r];
        acc[r * 3 + 1] = C[r] * rmask[r];
        acc[r * 3 + 2] = dpp_right(TL[r]) * rmask[r];
    }

    size_t vidx = (size_t)R * 64 + lane;
#pragma unroll
    for (int i = 0; i < 27; i++)
        craw[(size_t)i * NVOX + vidx] = (ushort)bf16b(acc[i]);

    size_t fb0 = (size_t)b * 3 * DHW + (size_t)z * HW + (size_t)y * Wn;
    float mfx, mfy, mfz;
    flow_head_mfma(acc, ccS, wid, lane, W1bf, b1, W2, b2, flow_forw, fb0,
                   mfx, mfy, mfz);

    float pv[10];
    fwd_losses_common(mfx, mfy, mfz, diff2, flow_g, mask_g, lane, y, z, b, fb0, pv);

    {
        PairGather pgF; float wsum;
        warp_pair_setup(mfx, mfy, mfz, lane, y, z, pgF, wsum);
        const float* f1b = feat1 + (size_t)b * BS;
        const float* f0c = feat0 + (size_t)b * BS + (size_t)z * HW + (size_t)y * Wn + lane;
        float s = 0.f;
#pragma unroll 4
        for (int c = 0; c < Cn; c++) {
            float g = gather8(f1b + (size_t)c * DHW, pgF);
            float d = g - f0c[(size_t)c * DHW];
            s = fmaf(d, d, s);
        }
        float vm = wsum * wsum;
        pv[2] = sqrtf(s + EPSF) * vm;
        pv[3] = vm;
    }

#pragma unroll
    for (int i = 0; i < 10; i++) {
        float val = pv[i];
        for (int off = 32; off; off >>= 1) val += __shfl_down(val, off, 64);
        pv[i] = val;
    }
    __shared__ float sred[10][4];
    if (lane == 0) {
#pragma unroll
        for (int i = 0; i < 10; i++) sred[i][wid] = pv[i];
    }
    __syncthreads();
    if (tid < 10) {
        atomicAdd(&accum[tid], sred[tid][0] + sred[tid][1] + sred[tid][2] + sred[tid][3]);
    }
}

// Backward direction derived from forward raw field:
// C_b[s][v] = C_f[2-s][v+s-1] (0 when OOB).
__global__ __launch_bounds__(256)
void corr_bwd_kernel(const ushort* __restrict__ craw,
                     const ushort* __restrict__ W1bf, const float* __restrict__ b1,
                     const float* __restrict__ W2, const float* __restrict__ b2,
                     float* __restrict__ flow_back) {
    __shared__ ushort ccSb[4][64][40];

    int tid = threadIdx.x;
    int lane = tid & 63;
    int wid = __builtin_amdgcn_readfirstlane(tid >> 6);

    int R = xcd_swz(blockIdx.x, 256) * 4 + wid;
    int y = R & 63, z = (R >> 6) & 63, b = R >> 12;

    float acc[27];
#pragma unroll
    for (int sz = 0; sz < 3; sz++) {
#pragma unroll
        for (int sy = 0; sy < 3; sy++) {
            int zz = z + sz - 1, yy = y + sy - 1;
            bool valid = (zz >= 0) && (zz < Dn) && (yy >= 0) && (yy < Hn);
            int zc = min(max(zz, 0), Dn - 1);
            int yc = min(max(yy, 0), Hn - 1);
            float m = valid ? 1.f : 0.f;
            const ushort* rowb = craw + (size_t)b * DHW + (size_t)zc * HW + (size_t)yc * Wn + lane;
            int base = (sz * 3 + sy) * 3;
            float v0 = bf2f(rowb[(size_t)(26 - base) * NVOX]);
            float v1 = bf2f(rowb[(size_t)(25 - base) * NVOX]);
            float v2 = bf2f(rowb[(size_t)(24 - base) * NVOX]);
            acc[base + 0] = dpp_left(v0) * m;
            acc[base + 1] = v1 * m;
            acc[base + 2] = dpp_right(v2) * m;
        }
    }

    size_t fb0 = (size_t)b * 3 * DHW + (size_t)z * HW + (size_t)y * Wn;
    float mfx, mfy, mfz;
    flow_head_mfma(acc, ccSb, wid, lane, W1bf, b1, W2, b2, flow_back, fb0,
                   mfx, mfy, mfz);
}

// Slim loss: cycle x2 + smoothness only.
__global__ __launch_bounds__(256)
void slim_loss_kernel(const float* __restrict__ flowf, const float* __restrict__ flowb,
                      float* __restrict__ accum) {
    int tid = threadIdx.x;
    int v = xcd_swz(blockIdx.x, 256) * 256 + tid;
    int x = v & 63, y = (v >> 6) & 63, z = (v >> 12) & 63, b = v >> 18;

    size_t sp = (size_t)z * HW + y * Wn + x;
    size_t f3 = (size_t)b * 3 * DHW + sp;

    float ffx = flowf[f3], ffy = flowf[f3 + DHW], ffz = flowf[f3 + 2 * DHW];
    float fbx = flowb[f3], fby = flowb[f3 + DHW], fbz = flowb[f3 + 2 * DHW];

    PairGather pgF; float wsumF;
    warp_pair_setup(ffx, ffy, ffz, x, y, z, pgF, wsumF);
    const float* fb_b = flowb + (size_t)b * 3 * DHW;
    float fbalx = gather8(fb_b, pgF);
    float fbaly = gather8(fb_b + DHW, pgF);
    float fbalz = gather8(fb_b + 2 * DHW, pgF);
    float cyc1 = sl1(ffx + fbalx) + sl1(ffy + fbaly) + sl1(ffz + fbalz);

    PairGather pgB; float wsumB;
    warp_pair_setup(fbx, fby, fbz, x, y, z, pgB, wsumB);
    const float* ff_b = flowf + (size_t)b * 3 * DHW;
    float ffalx = gather8(ff_b, pgB);
    float ffaly = gather8(ff_b + DHW, pgB);
    float ffalz = gather8(ff_b + 2 * DHW, pgB);
    float cyc2 = sl1(fbx + ffalx) + sl1(fby + ffaly) + sl1(fbz + ffalz);

    float sf = 0.f, sb2v = 0.f;
#pragma unroll
    for (int j = 0; j < 3; j++) {
        const float* pf = flowf + f3 + (size_t)j * DHW;
        float c0 = pf[0];
        float ddx = (x < Wn - 1) ? fabsf(pf[1] - c0) : 0.f;
        float ddy = (y < Hn - 1) ? fabsf(pf[Wn] - c0) : 0.f;
        sf += 2.f * ddx + ddy;
        const float* pb = flowb + f3 + (size_t)j * DHW;
        float c1 = pb[0];
        float ddx2 = (x < Wn - 1) ? fabsf(pb[1] - c1) : 0.f;
        float ddy2 = (y < Hn - 1) ? fabsf(pb[Wn] - c1) : 0.f;
        sb2v += 2.f * ddx2 + ddy2;
    }
    float smoothv = 0.5f * (sf * (1.f / 3.f) + sb2v * (1.f / 3.f));

    float pv[3] = { cyc1, cyc2, smoothv };
#pragma unroll
    for (int i = 0; i < 3; i++) {
        float val = pv[i];
        for (int off = 32; off; off >>= 1) val += __shfl_down(val, off, 64);
        pv[i] = val;
    }
    __shared__ float sred[3][4];
    int lane = tid & 63, wid = tid >> 6;
    if (lane == 0) {
#pragma unroll
        for (int i = 0; i < 3; i++) sred[i][wid] = pv[i];
    }
    __syncthreads();
    if (tid < 3) {
        atomicAdd(&accum[10 + tid], sred[tid][0] + sred[tid][1] + sred[tid][2] + sred[tid][3]);
    }
}

__global__ void finalize_kernel(const float* __restrict__ accum, float* __restrict__ out) {
    float hinge = accum[0] / (accum[1] + EPSF);
    float warp  = accum[2] / (accum[3] + EPSF);
    float l1b = 0.5f * (accum[4] / (accum[8] + EPSF) + accum[5] / (accum[9] + EPSF));
    float l2b = 0.5f * (accum[6] / (accum[8] + EPSF) + accum[7] / (accum[9] + EPSF));
    float n3 = 3.0f * (float)NVOX;
    float cyc = accum[10] / n3 + accum[11] / n3;
    float sm  = accum[12] / (float)NVOX;
    out[0] = hinge + cyc + l1b + l2b + warp + sm;
}

extern "C" void kernel_launch(void* const* d_in, const int* in_sizes, int n_in,
                              void* d_out, int out_size, void* d_ws, size_t ws_size,
                              hipStream_t stream) {
    const float* feat0  = (const float*)d_in[0];
    const float* feat1  = (const float*)d_in[1];
    const float* flow_g = (const float*)d_in[2];
    const float* mask_g = (const float*)d_in[3];
    const float* W1     = (const float*)d_in[4];
    const float* b1     = (const float*)d_in[5];
    const float* W2     = (const float*)d_in[6];
    const float* b2     = (const float*)d_in[7];

    float* out = (float*)d_out;
    float* accum = (float*)d_ws;                            // 13 floats @ 0
    ushort* W1bf = (ushort*)((char*)d_ws + 128);            // 5120 B
    const size_t FLOWB_OFF = 8192;
    const size_t FLOWB_BYTES = (size_t)Bn * 3 * DHW * sizeof(float);   // 6.29 MB
    float* flow_back = (float*)((char*)d_ws + FLOWB_OFF);
    const size_t CRAW_OFF = FLOWB_OFF + FLOWB_BYTES;
    const size_t CRAW_BYTES = (size_t)27 * NVOX * sizeof(ushort);      // 28.3 MB
    ushort* craw = (ushort*)((char*)d_ws + CRAW_OFF);
    const size_t PK1_OFF = CRAW_OFF + CRAW_BYTES;
    const size_t PK1_BYTES = (size_t)Cn * NVOX * sizeof(ushort);       // 33.6 MB
    uint2* pk1 = (uint2*)((char*)d_ws + PK1_OFF);
    float* flow_forw = out + 1;

    hipMemsetAsync(d_ws, 0, 64, stream);

    prep_kernel<<<dim3(8), dim3(256), 0, stream>>>(W1, W1bf);

    if (ws_size >= PK1_OFF + PK1_BYTES) {
        pack_kernel<<<dim3(NVOX / 256), dim3(256), 0, stream>>>(feat1, pk1);
        corr_fwd_packed<<<dim3(NVOX / 256), dim3(256), 0, stream>>>(
            feat0, pk1, W1bf, b1, W2, b2, flow_forw, flow_g, mask_g, accum, craw);
    } else {
        corr_fwd_f32<<<dim3(NVOX / 256), dim3(256), 0, stream>>>(
            feat0, feat1, W1bf, b1, W2, b2, flow_forw, flow_g, mask_g, accum, craw);
    }
    corr_bwd_kernel<<<dim3(NVOX / 256), dim3(256), 0, stream>>>(
        craw, W1bf, b1, W2, b2, flow_back);
    slim_loss_kernel<<<dim3(NVOX / 256), dim3(256), 0, stream>>>(flow_forw, flow_back, accum);
    finalize_kernel<<<1, 1, 0, stream>>>(accum, out);
}

// Round 21
// 138.410 us; speedup vs baseline: 1.1460x; 1.0125x over previous
//
#include <hip/hip_runtime.h>
#include <math.h>

#define EPSF 1e-6f

typedef __attribute__((ext_vector_type(8))) short short8;
typedef __attribute__((ext_vector_type(4))) float f32x4;
typedef __attribute__((ext_vector_type(4))) unsigned int u32x4;

constexpr int Bn = 2, Cn = 32, Dn = 64, Hn = 64, Wn = 64;
constexpr int HW  = Hn * Wn;          // 4096
constexpr int DHW = Dn * HW;          // 262144
constexpr int NVOX = Bn * DHW;        // 524288
constexpr size_t BS = (size_t)Cn * DHW;

// accum layout in ws:
// 0 hinge_num, 1 hinge_den, 2 warp_num, 3 warp_den,
// 4 l1_nz, 5 l1_yz, 6 l2_nz, 7 l2_yz, 8 nz_den, 9 yz_den,
// 10 cyc1, 11 cyc2, 12 smooth_sum

__device__ inline float sl1(float d) {
    float a = fabsf(d);
    return a < 1.f ? 0.5f * d * d : a - 0.5f;
}

__device__ inline int xcd_swz(int bid, int chunk) {
    return (bid & 7) * chunk + (bid >> 3);
}

__device__ inline float dpp_left(float v) {
    int r = __builtin_amdgcn_update_dpp(0, __float_as_int(v), 0x138, 0xF, 0xF, true);
    return __int_as_float(r);
}
__device__ inline float dpp_right(float v) {
    int r = __builtin_amdgcn_update_dpp(0, __float_as_int(v), 0x130, 0xF, 0xF, true);
    return __int_as_float(r);
}

__device__ inline unsigned int bf16b(float f) {
    return (__float_as_uint(f) + 0x8000u) >> 16;
}
__device__ inline unsigned int bfpack(float lo, float hi) {
    return bf16b(lo) | ((__float_as_uint(hi) + 0x8000u) & 0xffff0000u);
}
__device__ inline float bf2f(unsigned short u) {
    return __uint_as_float((unsigned int)u << 16);
}
__device__ inline float lo16(unsigned w) { return __uint_as_float(w << 16); }
__device__ inline float hi16(unsigned w) { return __uint_as_float(w & 0xffff0000u); }
// unpack channel j (0..7) from a u32x4 holding 8 bf16 channels
__device__ inline float unpk8(u32x4 q, int j) {
    unsigned w = q[j >> 1];
    return (j & 1) ? hi16(w) : lo16(w);
}

// Trilinear gather helpers (f32 path)
struct PairGather {
    int   pidx[4];
    int   sel[4];
    float w0[4], w1[4];
};

__device__ inline void warp_pair_setup(float flx, float fly, float flz,
                                       int x, int y, int z,
                                       PairGather& pg, float& wsum) {
    float xs = (float)x + flx, ys = (float)y + fly, zs = (float)z + flz;
    float xf = floorf(xs), yf = floorf(ys), zf = floorf(zs);
    float fx = xs - xf, fy = ys - yf, fz = zs - zf;
    int xi = (int)xf, yi = (int)yf, zi = (int)zf;

    int x0c = min(max(xi, 0), Wn - 1);
    bool xv0 = (xi >= 0) && (xi < Wn);
    bool xv1 = (xi + 1 >= 0) && (xi + 1 < Wn);
    int sel = (xi >= 0 && xi < Wn - 1) ? 1 : 0;
    float wx0 = xv0 ? (1.f - fx) : 0.f;
    float wx1 = xv1 ? fx : 0.f;

    wsum = 0.f;
#pragma unroll
    for (int cz = 0; cz < 2; cz++) {
        int zz = zi + cz;
        bool zv = (zz >= 0) && (zz < Dn);
        int zc = min(max(zz, 0), Dn - 1);
        float wz = (cz ? fz : 1.f - fz) * (zv ? 1.f : 0.f);
#pragma unroll
        for (int cy = 0; cy < 2; cy++) {
            int yy = yi + cy;
            bool yv = (yy >= 0) && (yy < Hn);
            int yc = min(max(yy, 0), Hn - 1);
            float wy = (cy ? fy : 1.f - fy) * (yv ? 1.f : 0.f);
            int k = cz * 2 + cy;
            int sp = (zc * Hn + yc) * Wn + x0c;
            pg.pidx[k] = min(sp, DHW - 2);
            pg.sel[k] = sel;
            float wzy = wz * wy;
            pg.w0[k] = wzy * wx0;
            pg.w1[k] = wzy * wx1;
            wsum += pg.w0[k] + pg.w1[k];
        }
    }
}

__device__ inline float gather8(const float* __restrict__ slab, const PairGather& pg) {
    float g = 0.f;
#pragma unroll
    for (int k = 0; k < 4; k++) {
        float2 v = *reinterpret_cast<const float2*>(slab + pg.pidx[k]);
        float second = pg.sel[k] ? v.y : v.x;
        g = fmaf(v.x, pg.w0[k], g);
        g = fmaf(second, pg.w1[k], g);
    }
    return g;
}

// One-time: W1 (64x27 f32) -> padded bf16 [n][k] with stride 40, k<27 else 0.
__global__ void prep_kernel(const float* __restrict__ W1, ushort* __restrict__ W1bf) {
    int i = blockIdx.x * 256 + threadIdx.x;
    if (i < 64 * 32) {
        int n = i >> 5, k = i & 31;
        float val = (k < 27) ? W1[n * 27 + k] : 0.f;
        W1bf[n * 40 + k] = (ushort)bf16b(val);
    }
}

// Pack feat1 into channel-group planes: pk1[p][vox] = 8 bf16 channels (16B).
__global__ __launch_bounds__(256)
void pack_kernel(const float* __restrict__ f1, u32x4* __restrict__ pk1) {
    int v = blockIdx.x * 256 + threadIdx.x;    // voxel 0..NVOX-1
    int b = v >> 18;
    int sp = v & (DHW - 1);
    const float* src = f1 + (size_t)b * BS + sp;
#pragma unroll
    for (int p = 0; p < 4; p++) {
        u32x4 q;
#pragma unroll
        for (int h = 0; h < 4; h++) {
            float c0 = src[(size_t)(8 * p + 2 * h) * DHW];
            float c1 = src[(size_t)(8 * p + 2 * h + 1) * DHW];
            q[h] = bfpack(c0, c1);
        }
        pk1[(size_t)p * NVOX + v] = q;
    }
}

// MFMA flow head (shared): relu -> l2norm -> bf16 LDS -> W1 MFMA -> leaky ->
// W2 -> store; returns lane's own-voxel flow.
__device__ __forceinline__ void flow_head_mfma(
        float* acc, ushort (*ccS)[64][40], int wid, int lane,
        const ushort* __restrict__ W1bf, const float* __restrict__ b1,
        const float* __restrict__ W2, const float* __restrict__ b2,
        float* __restrict__ flow_out, size_t fb0,
        float& mfx, float& mfy, float& mfz) {
    float ss = 0.f;
#pragma unroll
    for (int i = 0; i < 27; i++) {
        float r = acc[i] > 0.f ? acc[i] : 0.f;
        acc[i] = r;
        ss = fmaf(r, r, ss);
    }
    float inv = 1.0f / (sqrtf(ss) + EPSF);
#pragma unroll
    for (int i = 0; i < 27; i++) acc[i] *= inv;

    {
        unsigned int pk[16];
#pragma unroll
        for (int i = 0; i < 13; i++) pk[i] = bfpack(acc[2 * i], acc[2 * i + 1]);
        pk[13] = bfpack(acc[26], 0.f);
        pk[14] = 0u; pk[15] = 0u;
        uint2* rowp = reinterpret_cast<uint2*>(&ccS[wid][lane][0]);
#pragma unroll
        for (int i = 0; i < 8; i++) rowp[i] = make_uint2(pk[2 * i], pk[2 * i + 1]);
    }

    int c0 = lane & 15, oct = lane >> 4;

    short8 bfr[4];
#pragma unroll
    for (int t = 0; t < 4; t++)
        bfr[t] = *reinterpret_cast<const short8*>(W1bf + (size_t)(t * 16 + c0) * 40 + oct * 8);

    f32x4 b1v[4], w2f0[4], w2f1[4], w2f2[4];
#pragma unroll
    for (int mt = 0; mt < 4; mt++) {
        b1v[mt]  = *reinterpret_cast<const f32x4*>(b1 + mt * 16 + oct * 4);
        w2f0[mt] = *reinterpret_cast<const f32x4*>(W2 + mt * 16 + oct * 4);
        w2f1[mt] = *reinterpret_cast<const f32x4*>(W2 + 64 + mt * 16 + oct * 4);
        w2f2[mt] = *reinterpret_cast<const f32x4*>(W2 + 128 + mt * 16 + oct * 4);
    }
    float bb0 = b2[0], bb1 = b2[1], bb2 = b2[2];

#pragma unroll
    for (int nt = 0; nt < 4; nt++) {
        short8 afr = *reinterpret_cast<const short8*>(&ccS[wid][nt * 16 + c0][oct * 8]);
        f32x4 ac[4];
#pragma unroll
        for (int mt = 0; mt < 4; mt++) {
            f32x4 zero = {0.f, 0.f, 0.f, 0.f};
            ac[mt] = __builtin_amdgcn_mfma_f32_16x16x32_bf16(bfr[mt], afr, zero, 0, 0, 0);
        }
        float p0 = 0.f, p1 = 0.f, p2 = 0.f;
#pragma unroll
        for (int mt = 0; mt < 4; mt++) {
#pragma unroll
            for (int rg = 0; rg < 4; rg++) {
                float h = ac[mt][rg] + b1v[mt][rg];
                h = fmaxf(h, 0.01f * h);
                p0 = fmaf(w2f0[mt][rg], h, p0);
                p1 = fmaf(w2f1[mt][rg], h, p1);
                p2 = fmaf(w2f2[mt][rg], h, p2);
            }
        }
        p0 += __shfl_xor(p0, 16); p0 += __shfl_xor(p0, 32);
        p1 += __shfl_xor(p1, 16); p1 += __shfl_xor(p1, 32);
        p2 += __shfl_xor(p2, 16); p2 += __shfl_xor(p2, 32);
        if (oct == nt) {
            int vox = nt * 16 + c0;              // == lane
            mfx = p0 + bb0; mfy = p1 + bb1; mfz = p2 + bb2;
            flow_out[fb0 + vox]           = mfx;
            flow_out[fb0 + DHW + vox]     = mfy;
            flow_out[fb0 + 2 * DHW + vox] = mfz;
        }
    }
}

// Fused epilogue losses (shared by packed/f32 forward kernels).
__device__ __forceinline__ void fwd_losses_common(
        float mfx, float mfy, float mfz, float diff2,
        const float* __restrict__ flow_g, const float* __restrict__ mask_g,
        int lane, int y, int z, int b, size_t fb0, float* pv) {
    size_t fbase = fb0 + lane;
    float gx = flow_g[fbase], gy = flow_g[fbase + DHW], gz = flow_g[fbase + 2 * DHW];
    float mg = mask_g[(size_t)b * DHW + (size_t)z * HW + y * Wn + lane];

    float ag = fabsf(gx) + fabsf(gy) + fabsf(gz);
    float hmask = ag > 1.0f ? 1.f : 0.f;
    float hv = 0.2f - sqrtf(diff2 + EPSF);
    hv = hv > 0.f ? hv : 0.f;

    float dx0 = mfx - gx, dy0 = mfy - gy, dz0 = mfz - gz;
    float l1 = (sl1(dx0) + sl1(dy0) + sl1(dz0)) * (1.f / 3.f);
    float l2 = (dx0 * dx0 + dy0 * dy0 + dz0 * dz0) * (1.f / 3.f);
    float nz = (ag > 0.01f ? 1.f : 0.f) * mg;
    float yz = (1.f - nz) * mg;

    pv[0] = hv * hmask; pv[1] = hmask;
    pv[4] = l1 * nz;    pv[5] = l1 * yz;
    pv[6] = l2 * nz;    pv[7] = l2 * yz;
    pv[8] = nz;         pv[9] = yz;
}

// ---------------- PACKED forward kernel (16B row loads) ----------------
__global__ __launch_bounds__(256)
void corr_fwd_packed(const float* __restrict__ feat0, const u32x4* __restrict__ pk1,
                     const ushort* __restrict__ W1bf, const float* __restrict__ b1,
                     const float* __restrict__ W2, const float* __restrict__ b2,
                     float* __restrict__ flow_forw,
                     const float* __restrict__ flow_g, const float* __restrict__ mask_g,
                     float* __restrict__ accum, ushort* __restrict__ craw) {
    __shared__ ushort ccS[4][64][40];

    int tid = threadIdx.x;
    int lane = tid & 63;
    int wid = __builtin_amdgcn_readfirstlane(tid >> 6);

    int R = xcd_swz(blockIdx.x, 256) * 4 + wid;
    int y = R & 63, z = (R >> 6) & 63, b = R >> 12;

    // 9 packed row pointers (plane 0), advanced by NVOX per channel-group
    const u32x4* rp[9];
    float rmask[9];
    {
        int idx = 0;
#pragma unroll
        for (int dz = -1; dz <= 1; dz++) {
#pragma unroll
            for (int dy = -1; dy <= 1; dy++, idx++) {
                int zz = z + dz, yy = y + dy;
                bool valid = (zz >= 0) && (zz < Dn) && (yy >= 0) && (yy < Hn);
                int zc = min(max(zz, 0), Dn - 1);
                int yc = min(max(yy, 0), Hn - 1);
                rp[idx] = pk1 + (size_t)b * DHW + (size_t)zc * HW + (size_t)yc * Wn;
                rmask[idx] = valid ? 1.f : 0.f;
            }
        }
    }
    const float* ap = feat0 + (size_t)b * BS + (size_t)z * HW + (size_t)y * Wn;

    float C[9], TL[9], TR[9];
#pragma unroll
    for (int r = 0; r < 9; r++) { C[r] = 0.f; TL[r] = 0.f; TR[r] = 0.f; }
    float diff2 = 0.f;

#pragma unroll 1
    for (int p = 0; p < 4; p++) {
        u32x4 q[9];
#pragma unroll
        for (int r = 0; r < 9; r++) q[r] = rp[r][lane];
        float a8[8];
#pragma unroll
        for (int j = 0; j < 8; j++) a8[j] = ap[(size_t)j * DHW + lane];
        ap += (size_t)8 * DHW;
#pragma unroll
        for (int r = 0; r < 9; r++) rp[r] += NVOX;

#pragma unroll
        for (int j = 0; j < 8; j++) {
            float a = a8[j];
            float aL = dpp_left(a), aR = dpp_right(a);
            float ctr = unpk8(q[4], j);
            float d = ctr - a;
            diff2 = fmaf(d, d, diff2);
#pragma unroll
            for (int r = 0; r < 9; r++) {
                float rv = unpk8(q[r], j);
                C[r]  = fmaf(a,  rv, C[r]);
                TL[r] = fmaf(aL, rv, TL[r]);
                TR[r] = fmaf(aR, rv, TR[r]);
            }
        }
    }

    float acc[27];
#pragma unroll
    for (int r = 0; r < 9; r++) {
        acc[r * 3 + 0] = dpp_left(TR[r]) * rmask[r];
        acc[r * 3 + 1] = C[r] * rmask[r];
        acc[r * 3 + 2] = dpp_right(TL[r]) * rmask[r];
    }

    size_t vidx = (size_t)R * 64 + lane;
#pragma unroll
    for (int i = 0; i < 27; i++)
        craw[(size_t)i * NVOX + vidx] = (ushort)bf16b(acc[i]);

    size_t fb0 = (size_t)b * 3 * DHW + (size_t)z * HW + (size_t)y * Wn;
    float mfx, mfy, mfz;
    flow_head_mfma(acc, ccS, wid, lane, W1bf, b1, W2, b2, flow_forw, fb0,
                   mfx, mfy, mfz);

    float pv[10];
    fwd_losses_common(mfx, mfy, mfz, diff2, flow_g, mask_g, lane, y, z, b, fb0, pv);

    // feat-warp term on PACKED feat1: per plane, 4 corners x 2 u32x4 loads
    {
        PairGather pgF; float wsum;
        warp_pair_setup(mfx, mfy, mfz, lane, y, z, pgF, wsum);
        const u32x4* slab0 = pk1 + (size_t)b * DHW;
        const float* f0c = feat0 + (size_t)b * BS + (size_t)z * HW + (size_t)y * Wn + lane;
        float s = 0.f;
#pragma unroll 1
        for (int p = 0; p < 4; p++) {
            const u32x4* slab = slab0 + (size_t)p * NVOX;
            float g8[8] = {0.f, 0.f, 0.f, 0.f, 0.f, 0.f, 0.f, 0.f};
#pragma unroll
            for (int k = 0; k < 4; k++) {
                u32x4 q0 = slab[pgF.pidx[k]];
                u32x4 q1 = slab[pgF.pidx[k] + 1];
#pragma unroll
                for (int j = 0; j < 8; j++) {
                    float v0 = unpk8(q0, j);
                    float v1 = pgF.sel[k] ? unpk8(q1, j) : v0;
                    g8[j] = fmaf(v0, pgF.w0[k], g8[j]);
                    g8[j] = fmaf(v1, pgF.w1[k], g8[j]);
                }
            }
#pragma unroll
            for (int j = 0; j < 8; j++) {
                float d = g8[j] - f0c[(size_t)(8 * p + j) * DHW];
                s = fmaf(d, d, s);
            }
        }
        float vm = wsum * wsum;
        pv[2] = sqrtf(s + EPSF) * vm;
        pv[3] = vm;
    }

#pragma unroll
    for (int i = 0; i < 10; i++) {
        float val = pv[i];
        for (int off = 32; off; off >>= 1) val += __shfl_down(val, off, 64);
        pv[i] = val;
    }
    __shared__ float sred[10][4];
    if (lane == 0) {
#pragma unroll
        for (int i = 0; i < 10; i++) sred[i][wid] = pv[i];
    }
    __syncthreads();
    if (tid < 10) {
        atomicAdd(&accum[tid], sred[tid][0] + sred[tid][1] + sred[tid][2] + sred[tid][3]);
    }
}

// ---------------- f32 fallback forward kernel ----------------
__global__ __launch_bounds__(256)
void corr_fwd_f32(const float* __restrict__ feat0, const float* __restrict__ feat1,
                  const ushort* __restrict__ W1bf, const float* __restrict__ b1,
                  const float* __restrict__ W2, const float* __restrict__ b2,
                  float* __restrict__ flow_forw,
                  const float* __restrict__ flow_g, const float* __restrict__ mask_g,
                  float* __restrict__ accum, ushort* __restrict__ craw) {
    __shared__ ushort ccS[4][64][40];

    int tid = threadIdx.x;
    int lane = tid & 63;
    int wid = __builtin_amdgcn_readfirstlane(tid >> 6);

    int R = xcd_swz(blockIdx.x, 256) * 4 + wid;
    int y = R & 63, z = (R >> 6) & 63, b = R >> 12;

    const float* rp[9];
    float rmask[9];
    {
        int idx = 0;
#pragma unroll
        for (int dz = -1; dz <= 1; dz++) {
#pragma unroll
            for (int dy = -1; dy <= 1; dy++, idx++) {
                int zz = z + dz, yy = y + dy;
                bool valid = (zz >= 0) && (zz < Dn) && (yy >= 0) && (yy < Hn);
                int zc = min(max(zz, 0), Dn - 1);
                int yc = min(max(yy, 0), Hn - 1);
                rp[idx] = feat1 + (size_t)b * BS + (size_t)zc * HW + (size_t)yc * Wn;
                rmask[idx] = valid ? 1.f : 0.f;
            }
        }
    }
    const float* ap = feat0 + (size_t)b * BS + (size_t)z * HW + (size_t)y * Wn;

    float C[9], TL[9], TR[9];
#pragma unroll
    for (int r = 0; r < 9; r++) { C[r] = 0.f; TL[r] = 0.f; TR[r] = 0.f; }
    float diff2 = 0.f;

#pragma unroll 2
    for (int c = 0; c < Cn; c++) {
        float a = ap[lane];
        float rowv[9];
#pragma unroll
        for (int r = 0; r < 9; r++) rowv[r] = rp[r][lane];
        ap += DHW;
#pragma unroll
        for (int r = 0; r < 9; r++) rp[r] += DHW;

        float aL = dpp_left(a), aR = dpp_right(a);
        float d = rowv[4] - a;
        diff2 = fmaf(d, d, diff2);
#pragma unroll
        for (int r = 0; r < 9; r++) {
            float rv = rowv[r];
            C[r]  = fmaf(a,  rv, C[r]);
            TL[r] = fmaf(aL, rv, TL[r]);
            TR[r] = fmaf(aR, rv, TR[r]);
        }
    }

    float acc[27];
#pragma unroll
    for (int r = 0; r < 9; r++) {
        acc[r * 3 + 0] = dpp_left(TR[r]) * rmask[r];
        acc[r * 3 + 1] = C[r] * rmask[r];
        acc[r * 3 + 2] = dpp_right(TL[r]) * rmask[r];
    }

    size_t vidx = (size_t)R * 64 + lane;
#pragma unroll
    for (int i = 0; i < 27; i++)
        craw[(size_t)i * NVOX + vidx] = (ushort)bf16b(acc[i]);

    size_t fb0 = (size_t)b * 3 * DHW + (size_t)z * HW + (size_t)y * Wn;
    float mfx, mfy, mfz;
    flow_head_mfma(acc, ccS, wid, lane, W1bf, b1, W2, b2, flow_forw, fb0,
                   mfx, mfy, mfz);

    float pv[10];
    fwd_losses_common(mfx, mfy, mfz, diff2, flow_g, mask_g, lane, y, z, b, fb0, pv);

    {
        PairGather pgF; float wsum;
        warp_pair_setup(mfx, mfy, mfz, lane, y, z, pgF, wsum);
        const float* f1b = feat1 + (size_t)b * BS;
        const float* f0c = feat0 + (size_t)b * BS + (size_t)z * HW + (size_t)y * Wn + lane;
        float s = 0.f;
#pragma unroll 4
        for (int c = 0; c < Cn; c++) {
            float g = gather8(f1b + (size_t)c * DHW, pgF);
            float d = g - f0c[(size_t)c * DHW];
            s = fmaf(d, d, s);
        }
        float vm = wsum * wsum;
        pv[2] = sqrtf(s + EPSF) * vm;
        pv[3] = vm;
    }

#pragma unroll
    for (int i = 0; i < 10; i++) {
        float val = pv[i];
        for (int off = 32; off; off >>= 1) val += __shfl_down(val, off, 64);
        pv[i] = val;
    }
    __shared__ float sred[10][4];
    if (lane == 0) {
#pragma unroll
        for (int i = 0; i < 10; i++) sred[i][wid] = pv[i];
    }
    __syncthreads();
    if (tid < 10) {
        atomicAdd(&accum[tid], sred[tid][0] + sred[tid][1] + sred[tid][2] + sred[tid][3]);
    }
}

// Backward direction derived from forward raw field:
// C_b[s][v] = C_f[2-s][v+s-1] (0 when OOB).
__global__ __launch_bounds__(256)
void corr_bwd_kernel(const ushort* __restrict__ craw,
                     const ushort* __restrict__ W1bf, const float* __restrict__ b1,
                     const float* __restrict__ W2, const float* __restrict__ b2,
                     float* __restrict__ flow_back) {
    __shared__ ushort ccSb[4][64][40];

    int tid = threadIdx.x;
    int lane = tid & 63;
    int wid = __builtin_amdgcn_readfirstlane(tid >> 6);

    int R = xcd_swz(blockIdx.x, 256) * 4 + wid;
    int y = R & 63, z = (R >> 6) & 63, b = R >> 12;

    float acc[27];
#pragma unroll
    for (int sz = 0; sz < 3; sz++) {
#pragma unroll
        for (int sy = 0; sy < 3; sy++) {
            int zz = z + sz - 1, yy = y + sy - 1;
            bool valid = (zz >= 0) && (zz < Dn) && (yy >= 0) && (yy < Hn);
            int zc = min(max(zz, 0), Dn - 1);
            int yc = min(max(yy, 0), Hn - 1);
            float m = valid ? 1.f : 0.f;
            const ushort* rowb = craw + (size_t)b * DHW + (size_t)zc * HW + (size_t)yc * Wn + lane;
            int base = (sz * 3 + sy) * 3;
            float v0 = bf2f(rowb[(size_t)(26 - base) * NVOX]);
            float v1 = bf2f(rowb[(size_t)(25 - base) * NVOX]);
            float v2 = bf2f(rowb[(size_t)(24 - base) * NVOX]);
            acc[base + 0] = dpp_left(v0) * m;
            acc[base + 1] = v1 * m;
            acc[base + 2] = dpp_right(v2) * m;
        }
    }

    size_t fb0 = (size_t)b * 3 * DHW + (size_t)z * HW + (size_t)y * Wn;
    float mfx, mfy, mfz;
    flow_head_mfma(acc, ccSb, wid, lane, W1bf, b1, W2, b2, flow_back, fb0,
                   mfx, mfy, mfz);
}

// Slim loss: cycle x2 + smoothness only.
__global__ __launch_bounds__(256)
void slim_loss_kernel(const float* __restrict__ flowf, const float* __restrict__ flowb,
                      float* __restrict__ accum) {
    int tid = threadIdx.x;
    int v = xcd_swz(blockIdx.x, 256) * 256 + tid;
    int x = v & 63, y = (v >> 6) & 63, z = (v >> 12) & 63, b = v >> 18;

    size_t sp = (size_t)z * HW + y * Wn + x;
    size_t f3 = (size_t)b * 3 * DHW + sp;

    float ffx = flowf[f3], ffy = flowf[f3 + DHW], ffz = flowf[f3 + 2 * DHW];
    float fbx = flowb[f3], fby = flowb[f3 + DHW], fbz = flowb[f3 + 2 * DHW];

    PairGather pgF; float wsumF;
    warp_pair_setup(ffx, ffy, ffz, x, y, z, pgF, wsumF);
    const float* fb_b = flowb + (size_t)b * 3 * DHW;
    float fbalx = gather8(fb_b, pgF);
    float fbaly = gather8(fb_b + DHW, pgF);
    float fbalz = gather8(fb_b + 2 * DHW, pgF);
    float cyc1 = sl1(ffx + fbalx) + sl1(ffy + fbaly) + sl1(ffz + fbalz);

    PairGather pgB; float wsumB;
    warp_pair_setup(fbx, fby, fbz, x, y, z, pgB, wsumB);
    const float* ff_b = flowf + (size_t)b * 3 * DHW;
    float ffalx = gather8(ff_b, pgB);
    float ffaly = gather8(ff_b + DHW, pgB);
    float ffalz = gather8(ff_b + 2 * DHW, pgB);
    float cyc2 = sl1(fbx + ffalx) + sl1(fby + ffaly) + sl1(fbz + ffalz);

    float sf = 0.f, sb2v = 0.f;
#pragma unroll
    for (int j = 0; j < 3; j++) {
        const float* pf = flowf + f3 + (size_t)j * DHW;
        float c0 = pf[0];
        float ddx = (x < Wn - 1) ? fabsf(pf[1] - c0) : 0.f;
        float ddy = (y < Hn - 1) ? fabsf(pf[Wn] - c0) : 0.f;
        sf += 2.f * ddx + ddy;
        const float* pb = flowb + f3 + (size_t)j * DHW;
        float c1 = pb[0];
        float ddx2 = (x < Wn - 1) ? fabsf(pb[1] - c1) : 0.f;
        float ddy2 = (y < Hn - 1) ? fabsf(pb[Wn] - c1) : 0.f;
        sb2v += 2.f * ddx2 + ddy2;
    }
    float smoothv = 0.5f * (sf * (1.f / 3.f) + sb2v * (1.f / 3.f));

    float pv[3] = { cyc1, cyc2, smoothv };
#pragma unroll
    for (int i = 0; i < 3; i++) {
        float val = pv[i];
        for (int off = 32; off; off >>= 1) val += __shfl_down(val, off, 64);
        pv[i] = val;
    }
    __shared__ float sred[3][4];
    int lane = tid & 63, wid = tid >> 6;
    if (lane == 0) {
#pragma unroll
        for (int i = 0; i < 3; i++) sred[i][wid] = pv[i];
    }
    __syncthreads();
    if (tid < 3) {
        atomicAdd(&accum[10 + tid], sred[tid][0] + sred[tid][1] + sred[tid][2] + sred[tid][3]);
    }
}

__global__ void finalize_kernel(const float* __restrict__ accum, float* __restrict__ out) {
    float hinge = accum[0] / (accum[1] + EPSF);
    float warp  = accum[2] / (accum[3] + EPSF);
    float l1b = 0.5f * (accum[4] / (accum[8] + EPSF) + accum[5] / (accum[9] + EPSF));
    float l2b = 0.5f * (accum[6] / (accum[8] + EPSF) + accum[7] / (accum[9] + EPSF));
    float n3 = 3.0f * (float)NVOX;
    float cyc = accum[10] / n3 + accum[11] / n3;
    float sm  = accum[12] / (float)NVOX;
    out[0] = hinge + cyc + l1b + l2b + warp + sm;
}

extern "C" void kernel_launch(void* const* d_in, const int* in_sizes, int n_in,
                              void* d_out, int out_size, void* d_ws, size_t ws_size,
                              hipStream_t stream) {
    const float* feat0  = (const float*)d_in[0];
    const float* feat1  = (const float*)d_in[1];
    const float* flow_g = (const float*)d_in[2];
    const float* mask_g = (const float*)d_in[3];
    const float* W1     = (const float*)d_in[4];
    const float* b1     = (const float*)d_in[5];
    const float* W2     = (const float*)d_in[6];
    const float* b2     = (const float*)d_in[7];

    float* out = (float*)d_out;
    float* accum = (float*)d_ws;                            // 13 floats @ 0
    ushort* W1bf = (ushort*)((char*)d_ws + 128);            // 5120 B
    const size_t FLOWB_OFF = 8192;
    const size_t FLOWB_BYTES = (size_t)Bn * 3 * DHW * sizeof(float);   // 6.29 MB
    float* flow_back = (float*)((char*)d_ws + FLOWB_OFF);
    const size_t CRAW_OFF = FLOWB_OFF + FLOWB_BYTES;
    const size_t CRAW_BYTES = (size_t)27 * NVOX * sizeof(ushort);      // 28.3 MB
    ushort* craw = (ushort*)((char*)d_ws + CRAW_OFF);
    const size_t PK1_OFF = CRAW_OFF + CRAW_BYTES;
    const size_t PK1_BYTES = (size_t)Cn * NVOX * sizeof(ushort);       // 33.6 MB
    u32x4* pk1 = (u32x4*)((char*)d_ws + PK1_OFF);
    float* flow_forw = out + 1;

    hipMemsetAsync(d_ws, 0, 64, stream);

    prep_kernel<<<dim3(8), dim3(256), 0, stream>>>(W1, W1bf);

    if (ws_size >= PK1_OFF + PK1_BYTES) {
        pack_kernel<<<dim3(NVOX / 256), dim3(256), 0, stream>>>(feat1, pk1);
        corr_fwd_packed<<<dim3(NVOX / 256), dim3(256), 0, stream>>>(
            feat0, pk1, W1bf, b1, W2, b2, flow_forw, flow_g, mask_g, accum, craw);
    } else {
        corr_fwd_f32<<<dim3(NVOX / 256), dim3(256), 0, stream>>>(
            feat0, feat1, W1bf, b1, W2, b2, flow_forw, flow_g, mask_g, accum, craw);
    }
    corr_bwd_kernel<<<dim3(NVOX / 256), dim3(256), 0, stream>>>(
        craw, W1bf, b1, W2, b2, flow_back);
    slim_loss_kernel<<<dim3(NVOX / 256), dim3(256), 0, stream>>>(flow_forw, flow_back, accum);
    finalize_kernel<<<1, 1, 0, stream>>>(accum, out);
}